// Round 3
// baseline (517.626 us; speedup 1.0000x reference)
//
#include <hip/hip_runtime.h>

#define B_ 8
#define C_ 128
#define H_ 256
#define W_ 256
#define O_ 128
#define PAD 136   // 128 + 8 bf16: row stride 272 B = 68 dwords -> 4-bank rotation
#define WT 128    // pixels per workgroup

typedef __bf16 bf16x8 __attribute__((ext_vector_type(8)));
typedef float floatx4 __attribute__((ext_vector_type(4)));

__global__ __launch_bounds__(256, 4)
void activeshift_kernel(const float* __restrict__ x,
                        const float* __restrict__ theta,
                        const float* __restrict__ wdw,
                        const float* __restrict__ wpw,
                        float* __restrict__ out)
{
    __shared__ __align__(16) __bf16 s_lds[WT * PAD];  // [pixel][c] shifted x * wdw, bf16
    __shared__ __align__(16) float  t_q[C_ * 4];      // q00,q01,q10,q11 (wdw folded in)
    __shared__ __align__(16) int    t_o[C_ * 4];      // y0off,y1off,xoff,-

    // XCD chunk swizzle: 4096 wg / 8 XCDs -> 512 consecutive n per XCD (bijective)
    const int bid = blockIdx.x;
    const int n   = ((bid & 7) << 9) | (bid >> 3);
    const int wt  = n & 1;
    const int h   = (n >> 1) & (H_ - 1);
    const int b   = n >> 9;
    const int w0  = wt * WT;
    const int tid = threadIdx.x;
    const int m   = h + 1;              // padded row coord

    // ---- per-channel table: bilinear corner weights (y-validity + wdw folded) ----
    if (tid < C_) {
        float t0 = -theta[tid * 2 + 0];
        float t1 = -theta[tid * 2 + 1];
        float f0 = floorf(t0), f1 = floorf(t1);
        float dy = t0 - f0,    dx = t1 - f1;
        int ft0 = (int)f0, ft1 = (int)f1;
        int y0 = m + ft0, y1 = y0 + 1;                 // padded coords
        float dwv = wdw[tid];
        float wy0 = (y0 >= 1 && y0 <= H_) ? (1.0f - dy) * dwv : 0.0f;
        float wy1 = (y1 >= 1 && y1 <= H_) ? dy * dwv : 0.0f;
        int y0c = min(max(y0, 1), H_) - 1;             // safe data rows
        int y1c = min(max(y1, 1), H_) - 1;
        *(floatx4*)&t_q[tid * 4] = (floatx4){wy0 * (1.0f - dx), wy0 * dx,
                                             wy1 * (1.0f - dx), wy1 * dx};
        *(int4*)&t_o[tid * 4]    = (int4){y0c * W_, y1c * W_, w0 + ft1, 0};
    }
    __syncthreads();

    // ---- stage s: each thread = 1 pixel x 8 consecutive channels ----
    const int p     = tid & (WT - 1);                      // pixel in strip
    const int halfs = __builtin_amdgcn_readfirstlane(tid >> 7);
    const size_t HW = (size_t)H_ * W_;
    const float* xb = x + (size_t)b * C_ * HW;

    for (int it = 0; it < 8; ++it) {
        const int c0 = it * 16 + halfs * 8;                // wave-uniform
        union { bf16x8 v; __bf16 e[8]; } pk;
        #pragma unroll
        for (int cc = 0; cc < 8; ++cc) {
            const int c = c0 + cc;
            const floatx4 q = *(const floatx4*)&t_q[c * 4];   // uniform ds_read
            const int4   ov = *(const int4*)&t_o[c * 4];      // uniform ds_read
            const int y0off = __builtin_amdgcn_readfirstlane(ov.x);
            const int y1off = __builtin_amdgcn_readfirstlane(ov.y);
            const int xoff  = __builtin_amdgcn_readfirstlane(ov.z);
            const float* r0 = xb + (size_t)c * HW + y0off;    // scalar bases
            const float* r1 = xb + (size_t)c * HW + y1off;

            const int ix0 = p + xoff;                         // -1..256 for this input
            const int vo0 = min(max(ix0, 0), W_ - 1);         // v_med3
            const int vo1 = min(max(ix0 + 1, 0), W_ - 1);
            float v00 = r0[vo0], v01 = r0[vo1];
            float v10 = r1[vo0], v11 = r1[vo1];
            if ((unsigned)ix0       > (unsigned)(W_ - 1)) { v00 = 0.f; v10 = 0.f; }
            if ((unsigned)(ix0 + 1) > (unsigned)(W_ - 1)) { v01 = 0.f; v11 = 0.f; }

            pk.e[cc] = (__bf16)(q.x * v00 + q.y * v01 + q.z * v10 + q.w * v11);
        }
        *(bf16x8*)&s_lds[p * PAD + c0] = pk.v;               // 16 B write
    }
    __syncthreads();

    // ---- GEMM: out[o, pix] = sum_c wpw[o,c] * s[c,pix]; 4 waves, 64x64 each ----
    // A comes straight from global wpw (f32, L1/L2-resident), cvt to bf16 per k-step.
    const int wid  = tid >> 6;
    const int lane = tid & 63;
    const int wo   = (wid >> 1) * 64;   // o base of this wave
    const int wp   = (wid & 1) * 64;    // pixel base of this wave
    const int l15  = lane & 15;
    const int quad = lane >> 4;

    floatx4 acc[4][4];
    #pragma unroll
    for (int i = 0; i < 4; ++i)
        #pragma unroll
        for (int j = 0; j < 4; ++j)
            acc[i][j] = (floatx4){0.f, 0.f, 0.f, 0.f};

    #pragma unroll
    for (int k = 0; k < C_; k += 32) {
        bf16x8 bfr[4];
        #pragma unroll
        for (int j = 0; j < 4; ++j)  // B[k=c][n=pix]: n=lane&15, k=quad*8+j
            bfr[j] = *(const bf16x8*)&s_lds[(wp + j * 16 + l15) * PAD + k + quad * 8];
        #pragma unroll
        for (int i = 0; i < 4; ++i) {  // A[m=o][k=c]: m=lane&15, k=quad*8+j
            const float* ap = wpw + (size_t)(wo + i * 16 + l15) * C_ + k + quad * 8;
            floatx4 a0 = *(const floatx4*)ap;
            floatx4 a1 = *(const floatx4*)(ap + 4);
            bf16x8 af = { (__bf16)a0.x, (__bf16)a0.y, (__bf16)a0.z, (__bf16)a0.w,
                          (__bf16)a1.x, (__bf16)a1.y, (__bf16)a1.z, (__bf16)a1.w };
            #pragma unroll
            for (int j = 0; j < 4; ++j)
                acc[i][j] = __builtin_amdgcn_mfma_f32_16x16x32_bf16(af, bfr[j], acc[i][j], 0, 0, 0);
        }
    }

    // ---- store: D col = lane&15 = pixel, row = quad*4+reg = o ----
    float* ob = out + (size_t)b * O_ * HW + (size_t)h * W_;
    #pragma unroll
    for (int i = 0; i < 4; ++i) {
        #pragma unroll
        for (int j = 0; j < 4; ++j) {
            int pcol  = w0 + wp + j * 16 + l15;
            int obase = wo + i * 16 + quad * 4;
            float* op = ob + (size_t)obase * HW + pcol;
            #pragma unroll
            for (int r = 0; r < 4; ++r)
                op[(size_t)r * HW] = acc[i][j][r];
        }
    }
}

extern "C" void kernel_launch(void* const* d_in, const int* in_sizes, int n_in,
                              void* d_out, int out_size, void* d_ws, size_t ws_size,
                              hipStream_t stream) {
    const float* x     = (const float*)d_in[0];
    const float* theta = (const float*)d_in[1];
    const float* wdw   = (const float*)d_in[2];
    const float* wpw   = (const float*)d_in[3];
    float* out = (float*)d_out;
    activeshift_kernel<<<dim3(B_ * H_ * (W_ / WT)), dim3(256), 0, stream>>>(x, theta, wdw, wpw, out);
}

// Round 4
// 511.024 us; speedup vs baseline: 1.0129x; 1.0129x over previous
//
#include <hip/hip_runtime.h>

#define B_ 8
#define C_ 128
#define H_ 256
#define W_ 256
#define O_ 128
#define PAD 136   // 128 + 8 bf16: row stride 272 B = 68 dwords -> 4-bank rotation
#define WT 128    // pixels per workgroup

// ws layout (when ws_size >= WS_NEEDED):
//   [0, 32768)               bf16 w_eff[O_][C_] = bf16(wpw)   (wdw folded into q)
//   [32768, 32768 + 1 MiB)   32-B entry per (h,c): {float q[4]; int y0off,y1off,ft1,pad}
#define WS_WEFF 0
#define WS_TBL  32768
#define WS_NEEDED (32768 + H_ * C_ * 32)

typedef __bf16 bf16x8 __attribute__((ext_vector_type(8)));
typedef float floatx4 __attribute__((ext_vector_type(4)));

// ---------------- prep: one thread per (h,c) ----------------
__global__ __launch_bounds__(256)
void prep_kernel(const float* __restrict__ theta,
                 const float* __restrict__ wdw,
                 const float* __restrict__ wpw,
                 char* __restrict__ ws)
{
    const int gid = blockIdx.x * 256 + threadIdx.x;   // 0..32767 = h*128 + c
    if (gid < O_ * C_)
        ((__bf16*)(ws + WS_WEFF))[gid] = (__bf16)wpw[gid];

    const int h = gid >> 7;
    const int c = gid & (C_ - 1);
    float t0 = -theta[c * 2 + 0];
    float t1 = -theta[c * 2 + 1];
    float f0 = floorf(t0), f1 = floorf(t1);
    float dy = t0 - f0,    dx = t1 - f1;
    int ft0 = (int)f0, ft1 = (int)f1;
    int y0 = (h + 1) + ft0, y1 = y0 + 1;              // padded coords
    float dwv = wdw[c];
    float wy0 = (y0 >= 1 && y0 <= H_) ? (1.0f - dy) * dwv : 0.0f;
    float wy1 = (y1 >= 1 && y1 <= H_) ? dy * dwv : 0.0f;
    int y0c = min(max(y0, 1), H_) - 1;                // safe data rows
    int y1c = min(max(y1, 1), H_) - 1;

    char* e = ws + WS_TBL + (size_t)gid * 32;
    *(floatx4*)e        = (floatx4){wy0 * (1.0f - dx), wy0 * dx,
                                    wy1 * (1.0f - dx), wy1 * dx};
    *(int4*)(e + 16)    = (int4){y0c * W_, y1c * W_, ft1, 0};
}

// ---------------- main ----------------
template<bool USE_WS>
__global__ __launch_bounds__(256, 4)
void activeshift_kernel(const float* __restrict__ x,
                        const float* __restrict__ theta,
                        const float* __restrict__ wdw,
                        const float* __restrict__ wpw,
                        const char* __restrict__ ws,
                        float* __restrict__ out)
{
    __shared__ __align__(16) __bf16 s_lds[WT * PAD];  // [pixel][c] shifted x * wdw, bf16
    __shared__ __align__(16) float  t_q[C_ * 4];      // fallback path only
    __shared__ __align__(16) int    t_o[C_ * 4];      // fallback path only

    // XCD chunk swizzle: 4096 wg / 8 XCDs -> 512 consecutive n per XCD (bijective)
    const int bid = blockIdx.x;
    const int n   = ((bid & 7) << 9) | (bid >> 3);
    const int wt  = n & 1;
    const int h   = (n >> 1) & (H_ - 1);
    const int b   = n >> 9;
    const int w0  = wt * WT;
    const int tid = threadIdx.x;

    if (!USE_WS) {
        // ---- per-channel table in LDS (R3 path) ----
        if (tid < C_) {
            float t0 = -theta[tid * 2 + 0];
            float t1 = -theta[tid * 2 + 1];
            float f0 = floorf(t0), f1 = floorf(t1);
            float dy = t0 - f0,    dx = t1 - f1;
            int ft0 = (int)f0, ft1 = (int)f1;
            int y0 = (h + 1) + ft0, y1 = y0 + 1;
            float dwv = wdw[tid];
            float wy0 = (y0 >= 1 && y0 <= H_) ? (1.0f - dy) * dwv : 0.0f;
            float wy1 = (y1 >= 1 && y1 <= H_) ? dy * dwv : 0.0f;
            int y0c = min(max(y0, 1), H_) - 1;
            int y1c = min(max(y1, 1), H_) - 1;
            *(floatx4*)&t_q[tid * 4] = (floatx4){wy0 * (1.0f - dx), wy0 * dx,
                                                 wy1 * (1.0f - dx), wy1 * dx};
            *(int4*)&t_o[tid * 4]    = (int4){y0c * W_, y1c * W_, w0 + ft1, 0};
        }
        __syncthreads();
    }

    // ---- stage s: each thread = 1 pixel x 8 consecutive channels ----
    const int p     = tid & (WT - 1);                      // pixel in strip
    const int halfs = __builtin_amdgcn_readfirstlane(tid >> 7);
    const size_t HW = (size_t)H_ * W_;
    const float* xb = x + (size_t)b * C_ * HW;
    const int hC    = h * C_;

    for (int it = 0; it < 8; ++it) {
        const int c0 = it * 16 + halfs * 8;                // wave-uniform
        union { bf16x8 v; __bf16 e[8]; } pk;
        #pragma unroll
        for (int cc = 0; cc < 8; ++cc) {
            const int c = c0 + cc;
            floatx4 q; int y0off, y1off, xoff;
            if (USE_WS) {
                const int tix = __builtin_amdgcn_readfirstlane(hC + c);
                const char* e = ws + WS_TBL + (size_t)tix * 32;
                q = *(const floatx4*)e;                    // uniform -> s_load
                int4 ov = *(const int4*)(e + 16);          // uniform -> s_load
                y0off = ov.x; y1off = ov.y; xoff = ov.z + w0;
            } else {
                q = *(const floatx4*)&t_q[c * 4];
                int4 ov = *(const int4*)&t_o[c * 4];
                y0off = __builtin_amdgcn_readfirstlane(ov.x);
                y1off = __builtin_amdgcn_readfirstlane(ov.y);
                xoff  = __builtin_amdgcn_readfirstlane(ov.z);
            }
            const float* r0 = xb + (size_t)c * HW + y0off; // scalar bases
            const float* r1 = xb + (size_t)c * HW + y1off;

            const int ix0 = p + xoff;                      // -1..256 for this input
            const int vo0 = min(max(ix0, 0), W_ - 1);      // v_med3
            const int vo1 = min(max(ix0 + 1, 0), W_ - 1);
            float v00 = r0[vo0], v01 = r0[vo1];
            float v10 = r1[vo0], v11 = r1[vo1];
            if ((unsigned)ix0       > (unsigned)(W_ - 1)) { v00 = 0.f; v10 = 0.f; }
            if ((unsigned)(ix0 + 1) > (unsigned)(W_ - 1)) { v01 = 0.f; v11 = 0.f; }

            pk.e[cc] = (__bf16)(q.x * v00 + q.y * v01 + q.z * v10 + q.w * v11);
        }
        *(bf16x8*)&s_lds[p * PAD + c0] = pk.v;             // 16 B write
    }
    __syncthreads();

    // ---- GEMM: out[o, pix] = sum_c w[o,c] * s[c,pix]; 4 waves, 64x64 each ----
    const int wid  = tid >> 6;
    const int lane = tid & 63;
    const int wo   = (wid >> 1) * 64;   // o base of this wave
    const int wp   = (wid & 1) * 64;    // pixel base of this wave
    const int l15  = lane & 15;
    const int quad = lane >> 4;

    floatx4 acc[4][4];
    #pragma unroll
    for (int i = 0; i < 4; ++i)
        #pragma unroll
        for (int j = 0; j < 4; ++j)
            acc[i][j] = (floatx4){0.f, 0.f, 0.f, 0.f};

    const __bf16* weff = (const __bf16*)(ws + WS_WEFF);

    #pragma unroll
    for (int k = 0; k < C_; k += 32) {
        bf16x8 bfr[4];
        #pragma unroll
        for (int j = 0; j < 4; ++j)  // B[k=c][n=pix]: n=lane&15, k=quad*8+j
            bfr[j] = *(const bf16x8*)&s_lds[(wp + j * 16 + l15) * PAD + k + quad * 8];
        #pragma unroll
        for (int i = 0; i < 4; ++i) {  // A[m=o][k=c]: m=lane&15, k=quad*8+j
            bf16x8 af;
            if (USE_WS) {
                af = *(const bf16x8*)(weff + (size_t)(wo + i * 16 + l15) * C_ + k + quad * 8);
            } else {
                const float* ap = wpw + (size_t)(wo + i * 16 + l15) * C_ + k + quad * 8;
                floatx4 a0 = *(const floatx4*)ap;
                floatx4 a1 = *(const floatx4*)(ap + 4);
                af = (bf16x8){ (__bf16)a0.x, (__bf16)a0.y, (__bf16)a0.z, (__bf16)a0.w,
                               (__bf16)a1.x, (__bf16)a1.y, (__bf16)a1.z, (__bf16)a1.w };
            }
            #pragma unroll
            for (int j = 0; j < 4; ++j)
                acc[i][j] = __builtin_amdgcn_mfma_f32_16x16x32_bf16(af, bfr[j], acc[i][j], 0, 0, 0);
        }
    }

    // ---- store: D col = lane&15 = pixel, row = quad*4+reg = o ----
    float* ob = out + (size_t)b * O_ * HW + (size_t)h * W_;
    #pragma unroll
    for (int i = 0; i < 4; ++i) {
        #pragma unroll
        for (int j = 0; j < 4; ++j) {
            int pcol  = w0 + wp + j * 16 + l15;
            int obase = wo + i * 16 + quad * 4;
            float* op = ob + (size_t)obase * HW + pcol;
            #pragma unroll
            for (int r = 0; r < 4; ++r)
                op[(size_t)r * HW] = acc[i][j][r];
        }
    }
}

extern "C" void kernel_launch(void* const* d_in, const int* in_sizes, int n_in,
                              void* d_out, int out_size, void* d_ws, size_t ws_size,
                              hipStream_t stream) {
    const float* x     = (const float*)d_in[0];
    const float* theta = (const float*)d_in[1];
    const float* wdw   = (const float*)d_in[2];
    const float* wpw   = (const float*)d_in[3];
    float* out = (float*)d_out;
    const dim3 grid(B_ * H_ * (W_ / WT));

    const bool use_ws = (d_ws != nullptr) && (ws_size >= (size_t)WS_NEEDED);
    if (use_ws) {
        prep_kernel<<<dim3(H_ * C_ / 256), dim3(256), 0, stream>>>(theta, wdw, wpw, (char*)d_ws);
        activeshift_kernel<true><<<grid, dim3(256), 0, stream>>>(x, theta, wdw, wpw, (const char*)d_ws, out);
    } else {
        activeshift_kernel<false><<<grid, dim3(256), 0, stream>>>(x, theta, wdw, wpw, nullptr, out);
    }
}